// Round 13
// baseline (95.487 us; speedup 1.0000x reference)
//
#include <hip/hip_runtime.h>
#include <math.h>

#define BATCH 4
#define HLR 256
#define WLR 256
#define HHR 512
#define WHR 512

typedef short s8v __attribute__((ext_vector_type(8)));
typedef float f4v __attribute__((ext_vector_type(4)));

__device__ __forceinline__ ushort f2bf(float f) {
    uint u = __builtin_bit_cast(uint, f);
    uint r = (u + 0x7FFFu + ((u >> 16) & 1u)) >> 16;
    return (ushort)r;
}
__device__ __forceinline__ float bf2f(ushort u) {
    return __builtin_bit_cast(float, ((uint)u) << 16);
}

// --------- Effective upsample weight: Av(d, e_idx, t_idx), taps t-1 in {-1..2} -----
__device__ __forceinline__ float Avf(int d, int e, int t) {
    int mm = d + e - 1;
    int par = mm & 1;
    int jr = (mm - par) >> 1;
    int j2 = jr + (par ? 1 : -1);
    float a = 0.f;
    if (t == jr + 1) a += 0.75f;
    if (t == j2 + 1) a += 0.25f;
    return a;
}

// ============ Launch 1: z<12 -> fused down+gain+bilateral+gamma ; z==12 -> weight prep
__global__ void __launch_bounds__(256) k_front(
    const float* __restrict__ x, const float* __restrict__ gains,
    const float* __restrict__ sigp, const float* __restrict__ gamp,
    float* __restrict__ xlr,
    const float* __restrict__ w1, const float* __restrict__ w2,
    const float* __restrict__ w3, ushort* __restrict__ Bp1,
    ushort* __restrict__ Bp2, ushort* __restrict__ Bp3) {
    const int z = blockIdx.z;
    const int tid = threadIdx.x;
    if (z < 12) {
        __shared__ float tile[20][20];
        const int tx = tid & 15, ty = tid >> 4;
        const int w0 = blockIdx.x * 16, h0 = blockIdx.y * 16;
        const int bc = z;
        const int c = bc % 3;
        const float* src = x + (size_t)bc * (HHR * WHR);
        const float gain = gains[c];

        const float cw0 = -0.09375f, cw1 = 0.59375f, cw2 = 0.59375f, cw3 = -0.09375f;
        for (int i = tid; i < 400; i += 256) {
            int r = i / 20, cc = i - r * 20;
            int hh = h0 + r - 2, ww = w0 + cc - 2;
            float acc = 0.f;
#pragma unroll
            for (int kh = 0; kh < 4; ++kh) {
                int sh = 2 * hh + kh - 1;
                sh = sh < 0 ? 0 : (sh > HHR - 1 ? HHR - 1 : sh);
                const float* row = src + (size_t)sh * WHR;
                float rr = 0.f;
#pragma unroll
                for (int kw = 0; kw < 4; ++kw) {
                    int sw = 2 * ww + kw - 1;
                    sw = sw < 0 ? 0 : (sw > WHR - 1 ? WHR - 1 : sw);
                    float wk = (kw == 0) ? cw0 : (kw == 1) ? cw1 : (kw == 2) ? cw2 : cw3;
                    rr = fmaf(wk, row[sw], rr);
                }
                float wk = (kh == 0) ? cw0 : (kh == 1) ? cw1 : (kh == 2) ? cw2 : cw3;
                acc = fmaf(wk, rr, acc);
            }
            tile[r][cc] = acc * gain;
        }
        __syncthreads();

        const int h = h0 + ty, w = w0 + tx;
        float sigma = sigp[0];
        float inv2s2 = 1.0f / (2.0f * sigma * sigma);
        float invg = 1.0f / gamp[0];
        const float sp0 = 0.13533528f;
        const float sp1 = 0.60653066f;

        float center = tile[ty + 2][tx + 2];
        float wsum = 0.f, psum = 0.f;
#pragma unroll
        for (int i = 0; i < 5; ++i) {
            int sh = h + i - 2;
            sh = sh < 0 ? -sh : (sh > HLR - 1 ? 2 * (HLR - 1) - sh : sh);
            int lr = sh - h0 + 2;
            float spi = (i == 0 || i == 4) ? sp0 : (i == 2 ? 1.0f : sp1);
#pragma unroll
            for (int j = 0; j < 5; ++j) {
                int sw = w + j - 2;
                sw = sw < 0 ? -sw : (sw > WLR - 1 ? 2 * (WLR - 1) - sw : sw);
                int lc = sw - w0 + 2;
                float spj = (j == 0 || j == 4) ? sp0 : (j == 2 ? 1.0f : sp1);
                float p = tile[lr][lc];
                float d = p - center;
                float cwt = __expf(-d * d * inv2s2) * spi * spj;
                wsum += cwt;
                psum = fmaf(cwt, p, psum);
            }
        }
        float v = psum / (wsum + 1e-8f);
        v = fminf(fmaxf(v, 1e-8f), 1.0f);
        xlr[(size_t)bc * (HLR * WLR) + h * WLR + w] = __powf(v, invg);
    } else {
        int bx = blockIdx.y * 16 + blockIdx.x;  // 0..255, 232 used
        if (bx >= 232) return;
        if (bx < 144) {
            int t4 = bx * 256 + tid;
            int j = t4 & 7;
            int l = (t4 >> 3) & 63;
            int g = (t4 >> 9) & 3;
            int s = t4 >> 11;
            int k = 32 * s + (l >> 4) * 8 + j;
            int t = k >> 6;
            int ic = k & 63;
            int oc = g * 16 + (l & 15);
            Bp2[t4] = f2bf(w2[(size_t)(oc * 64 + ic) * 9 + t]);
        } else if (bx < 208) {
            int t4 = (bx - 144) * 256 + tid;
            int j = t4 & 7;
            int l = (t4 >> 3) & 63;
            int s = t4 >> 9;
            int col = l & 15;
            float v = 0.f;
            if (col < 12) {
                int p = col / 3, o = col % 3;
                int dy = p >> 1, dx = p & 1;
                int k = s * 32 + (l >> 4) * 8 + j;
                int tap = k >> 6, ic = k & 63;
                int ty = tap >> 2, tx = tap & 3;
#pragma unroll
                for (int oh = 0; oh < 3; ++oh)
#pragma unroll
                    for (int ow = 0; ow < 3; ++ow)
                        v += w3[(size_t)(o * 64 + ic) * 9 + oh * 3 + ow] *
                             Avf(dy, oh, ty) * Avf(dx, ow, tx);
            }
            Bp3[t4] = f2bf(v);
        } else {
            int t4 = (bx - 208) * 256 + tid;
            int j = t4 & 7;
            int l = (t4 >> 3) & 63;
            int g = (t4 >> 9) & 3;
            int s = t4 >> 11;
            int k = s * 32 + (l >> 4) * 8 + j;
            int oc = g * 16 + (l & 15);
            float v = 0.f;
            if (k < 75) {
                int tap = k / 3, ic = k % 3;
                v = w1[(size_t)oc * 75 + ic * 25 + tap];
            }
            Bp1[t4] = f2bf(v);
        }
    }
}

// ============ Launch 2: conv1 3->64, 5x5, pad 2, relu — MFMA + coalesced epilogue ==
__global__ void __launch_bounds__(256) k_conv1_mfma(
    const float* __restrict__ xlr, const ushort* __restrict__ Bp,
    const float* __restrict__ b1, ushort* __restrict__ y1) {
    __shared__ float rawt[3][8][20];
    __shared__ __align__(16) ushort Alds[64 * 104];
    const int tid = threadIdx.x;
    const int w0 = blockIdx.x * 16;
    const int h0 = blockIdx.y * 4;
    const int b = blockIdx.z;

    for (int i = tid; i < 480; i += 256) {
        int ch = i / 160;
        int rem = i - ch * 160;
        int r = rem / 20, c = rem - r * 20;
        int gh = h0 + r - 2, gw = w0 + c - 2;
        float v = 0.f;
        if (gh >= 0 && gh < HLR && gw >= 0 && gw < WLR)
            v = xlr[(size_t)(b * 3 + ch) * (HLR * WLR) + gh * WLR + gw];
        rawt[ch][r][c] = v;
    }
    __syncthreads();

    {
        const int pos = tid >> 2;
        const int kq = tid & 3;
        const int f = pos >> 4;
        const int wl = pos & 15;
#pragma unroll
        for (int m = 0; m < 3; ++m) {
            uint pk[4];
#pragma unroll
            for (int e2 = 0; e2 < 4; ++e2) {
                ushort lo, hi;
#pragma unroll
                for (int h2 = 0; h2 < 2; ++h2) {
                    int i = m * 8 + e2 * 2 + h2;
                    int t0 = i / 3;
                    int ic = i - t0 * 3;
                    int tap = kq * 8 + t0;
                    float val = 0.f;
                    if (tap < 25) {
                        int kh = tap / 5, kw = tap - (tap / 5) * 5;
                        val = rawt[ic][f + kh][wl + kw];
                    }
                    if (h2 == 0) lo = f2bf(val); else hi = f2bf(val);
                }
                pk[e2] = (uint)lo | ((uint)hi << 16);
            }
            *(int4*)(Alds + pos * 104 + kq * 24 + m * 8) =
                make_int4(pk[0], pk[1], pk[2], pk[3]);
        }
    }
    __syncthreads();

    const int lane = tid & 63;
    const int wv = tid >> 6;
    const int l15 = lane & 15;
    const int lgrp = lane >> 4;

    f4v acc[4];
#pragma unroll
    for (int f = 0; f < 4; ++f) acc[f] = (f4v){0.f, 0.f, 0.f, 0.f};

#pragma unroll
    for (int s = 0; s < 3; ++s) {
        s8v bfrag = *(const s8v*)(Bp + ((size_t)(s * 4 + wv) * 64 + lane) * 8);
#pragma unroll
        for (int f = 0; f < 4; ++f) {
            const ushort* ap = Alds + (f * 16 + l15) * 104 + s * 32 + lgrp * 8;
            s8v afrag = *(const s8v*)ap;
            acc[f] = __builtin_amdgcn_mfma_f32_16x16x32_bf16(afrag, bfrag, acc[f], 0, 0, 0);
        }
    }

    __syncthreads();
    int oc = wv * 16 + l15;
    float bias = b1[oc];
#pragma unroll
    for (int f = 0; f < 4; ++f) {
#pragma unroll
        for (int r = 0; r < 4; ++r) {
            int pos = f * 16 + lgrp * 4 + r;
            Alds[pos * 64 + oc] = f2bf(fmaxf(acc[f][r] + bias, 0.f));
        }
    }
    __syncthreads();
    const size_t base = (size_t)b * HLR * WLR * 64;
#pragma unroll
    for (int i = tid; i < 512; i += 256) {
        int pos = i >> 3, c = i & 7;
        int f = pos >> 4, wcol = pos & 15;
        int4 v = *(const int4*)(Alds + pos * 64 + c * 8);
        *(int4*)(y1 + base + (size_t)((h0 + f) * WLR + (w0 + wcol)) * 64 + c * 8) = v;
    }
}

// ============ Launch 3: conv2 64->64, 3x3, pad1, relu — MFMA + coalesced epilogue ==
__global__ void __launch_bounds__(256) k_conv2_mfma(
    const ushort* __restrict__ y1, const ushort* __restrict__ Bprep,
    const float* __restrict__ b2, ushort* __restrict__ y2) {
    __shared__ ushort lds[6 * 18 * 64];  // 13824 B
    const int tid = threadIdx.x;
    const int w0 = blockIdx.x * 16;
    const int h0 = blockIdx.y * 4;
    const int b = blockIdx.z;
    const size_t base = (size_t)b * HLR * WLR * 64;

    for (int i = tid; i < 864; i += 256) {
        int c = i & 7;
        int pos = i >> 3;
        int r = pos / 18;
        int cc = pos - r * 18;
        int gh = h0 + r - 1, gw = w0 + cc - 1;
        int4 v = make_int4(0, 0, 0, 0);
        if (gh >= 0 && gh < HLR && gw >= 0 && gw < WLR)
            v = *(const int4*)(y1 + base + (size_t)(gh * WLR + gw) * 64 + c * 8);
        int byte = pos * 128 + ((c * 16) ^ ((pos & 7) << 4));
        *(int4*)((char*)lds + byte) = v;
    }
    __syncthreads();

    const int lane = tid & 63;
    const int wv = tid >> 6;
    const int l15 = lane & 15;
    const int lgrp = lane >> 4;

    f4v acc[4];
#pragma unroll
    for (int f = 0; f < 4; ++f) acc[f] = (f4v){0.f, 0.f, 0.f, 0.f};

    const ushort* bp = Bprep + ((size_t)wv * 64 + lane) * 8;
#pragma unroll
    for (int s = 0; s < 18; ++s) {
        const int t = s >> 1;
        const int dh = t / 3 - 1;
        const int dw = t % 3 - 1;
        const int icb = (s & 1) * 64 + lgrp * 16;
        s8v bfrag = *(const s8v*)(bp + (size_t)s * (4 * 64 * 8));
#pragma unroll
        for (int f = 0; f < 4; ++f) {
            int sp = (f + dh + 1) * 18 + (l15 + dw + 1);
            int byte = sp * 128 + (icb ^ ((sp & 7) << 4));
            s8v afrag = *(const s8v*)((const char*)lds + byte);
            acc[f] = __builtin_amdgcn_mfma_f32_16x16x32_bf16(afrag, bfrag, acc[f], 0, 0, 0);
        }
    }

    __syncthreads();
    int oc = wv * 16 + l15;
    float bias = b2[oc];
#pragma unroll
    for (int f = 0; f < 4; ++f) {
#pragma unroll
        for (int r = 0; r < 4; ++r) {
            int pos = f * 16 + lgrp * 4 + r;
            lds[pos * 64 + oc] = f2bf(fmaxf(acc[f][r] + bias, 0.f));
        }
    }
    __syncthreads();
#pragma unroll
    for (int i = tid; i < 512; i += 256) {
        int pos = i >> 3, c = i & 7;
        int f = pos >> 4, wcol = pos & 15;
        int4 v = *(const int4*)(lds + pos * 64 + c * 8);
        *(int4*)(y2 + base + (size_t)((h0 + f) * WLR + (w0 + wcol)) * 64 + c * 8) = v;
    }
}

// ============ Launch 4: upc3 interior — B-fragments staged in LDS ==================
// 256 thr = 4 waves, wave = 2 LR rows; inner loop all-LDS (conv2 recipe).
// LDS: A-tile 26.75 KB + Bp3 copy 16 KB = 42.75 KB -> 3 blocks/CU.
__global__ void __launch_bounds__(256) k_upc3(
    const ushort* __restrict__ y2, const ushort* __restrict__ Bp,
    const float* __restrict__ b3, float* __restrict__ xsr) {
    __shared__ ushort lds[11 * 19 * 64];            // A tile (first 6 KB reused for out)
    __shared__ __align__(16) ushort Blds[32 * 512]; // 16384 B: B-fragments
    const int tid = threadIdx.x;
    const int w0 = blockIdx.x * 16;
    const int h0 = blockIdx.y * 8;
    const int b = blockIdx.z;
    const size_t base = (size_t)b * HLR * WLR * 64;
    const int lane = tid & 63;
    const int wv = tid >> 6;

    // stage A: rows h0-1..h0+9, cols w0-1..w0+17, edge-clamped, swizzled
    for (int i = tid; i < 1672; i += 256) {  // 209 pos x 8 chunks
        int c = i & 7;
        int pos = i >> 3;
        int r = pos / 19, cc = pos - r * 19;
        int gh = h0 + r - 1, gw = w0 + cc - 1;
        gh = gh < 0 ? 0 : (gh > HLR - 1 ? HLR - 1 : gh);
        gw = gw < 0 ? 0 : (gw > WLR - 1 ? WLR - 1 : gw);
        int4 v = *(const int4*)(y2 + base + (size_t)(gh * WLR + gw) * 64 + c * 8);
        int byte = pos * 128 + ((c * 16) ^ ((pos & 7) << 4));
        *(int4*)((char*)lds + byte) = v;
    }
    // stage B: straight copy of Bp3 (same 16 KB for every block -> L2 broadcast)
    for (int i = tid; i < 2048; i += 256)
        ((int4*)Blds)[i] = ((const int4*)Bp)[i];
    __syncthreads();

    const int l15 = lane & 15;
    const int lgrp = lane >> 4;
    const int rowbase = wv * 2;

    f4v acc[2];
#pragma unroll
    for (int f = 0; f < 2; ++f) acc[f] = (f4v){0.f, 0.f, 0.f, 0.f};

#pragma unroll
    for (int ichalf = 0; ichalf < 2; ++ichalf) {
#pragma unroll
        for (int tx = 0; tx < 4; ++tx) {
            s8v av[5];
#pragma unroll
            for (int rr = 0; rr < 5; ++rr) {
                int pos = (rowbase + rr) * 19 + (l15 + tx);
                int byte = pos * 128 + ((ichalf * 64 + lgrp * 16) ^ ((pos & 7) << 4));
                av[rr] = *(const s8v*)((const char*)lds + byte);
            }
#pragma unroll
            for (int ty = 0; ty < 4; ++ty) {
                int s = (ty * 4 + tx) * 2 + ichalf;
                s8v bfrag = *(const s8v*)(Blds + s * 512 + lane * 8);
#pragma unroll
                for (int f = 0; f < 2; ++f)
                    acc[f] = __builtin_amdgcn_mfma_f32_16x16x32_bf16(
                        av[f + ty], bfrag, acc[f], 0, 0, 0);
            }
        }
    }

    // epilogue: scatter to LDS float tile [o][nn 0..15][mm 0..31], coalesced sweeps
    __syncthreads();
    float* ldsf = (float*)lds;
    if (l15 < 12) {
        int p_ = l15 / 3;
        int o_ = l15 - p_ * 3;
        int dy = p_ >> 1, dx = p_ & 1;
        float bias = b3[o_];
#pragma unroll
        for (int f = 0; f < 2; ++f) {
            int nn = 2 * (rowbase + f) + dy;
#pragma unroll
            for (int r = 0; r < 4; ++r) {
                int mm = 2 * (lgrp * 4 + r) + dx;
                ldsf[(o_ * 16 + nn) * 32 + mm] = acc[f][r] + bias;
            }
        }
    }
    __syncthreads();
#pragma unroll
    for (int j = tid; j < 1536; j += 256) {
        int o = j >> 9;
        int rem = j & 511;
        int nn = rem >> 5, mm = rem & 31;
        int n = 2 * h0 + nn;
        int m = 2 * w0 + mm;
        if (n != 0 && n != HHR - 1 && m != 0 && m != WHR - 1)
            xsr[(size_t)(b * 3 + o) * HHR * WHR + (size_t)n * WHR + m] = ldsf[j];
    }
}

// ============ Launch 5: frame fixup — w3 staged in LDS, 8 threads per pixel ========
__global__ void __launch_bounds__(256) k_fixframe(
    const ushort* __restrict__ y2, const float* __restrict__ w3,
    const float* __restrict__ b3, float* __restrict__ xsr) {
    __shared__ float w3s[1728];  // 3*64*9 f32
    const int tid = threadIdx.x;
    for (int i = tid; i < 1728; i += 256) w3s[i] = w3[i];
    __syncthreads();

    int t = blockIdx.x * 256 + tid;
    int pix = t >> 3;
    int icg = t & 7;
    if (pix >= BATCH * 3 * 2044) return;
    int b = pix / (3 * 2044);
    int rem = pix - b * (3 * 2044);
    int o = rem / 2044;
    int p = rem - o * 2044;
    int n, m;
    if (p < 512) { n = 0; m = p; }
    else if (p < 1024) { n = 511; m = p - 512; }
    else if (p < 1534) { n = p - 1024 + 1; m = 0; }
    else { n = p - 1534 + 1; m = 511; }

    const ushort* Y = y2 + (size_t)b * HLR * WLR * 64 + icg * 8;
    const float* wb = w3s + (size_t)(o * 64 + icg * 8) * 9;
    float acc = 0.f;
#pragma unroll
    for (int oh = 0; oh < 3; ++oh) {
        int r = n - 1 + oh;
        if (r < 0 || r >= HHR) continue;
        int pr = r & 1;
        int jr = (r - pr) >> 1;
        int j2 = jr + (pr ? 1 : -1);
        j2 = j2 < 0 ? 0 : (j2 > HLR - 1 ? HLR - 1 : j2);
#pragma unroll
        for (int ow = 0; ow < 3; ++ow) {
            int c = m - 1 + ow;
            if (c < 0 || c >= WHR) continue;
            int pc = c & 1;
            int kc = (c - pc) >> 1;
            int k2 = kc + (pc ? 1 : -1);
            k2 = k2 < 0 ? 0 : (k2 > WLR - 1 ? WLR - 1 : k2);
            s8v y00 = *(const s8v*)(Y + (size_t)(jr * WLR + kc) * 64);
            s8v y01 = *(const s8v*)(Y + (size_t)(jr * WLR + k2) * 64);
            s8v y10 = *(const s8v*)(Y + (size_t)(j2 * WLR + kc) * 64);
            s8v y11 = *(const s8v*)(Y + (size_t)(j2 * WLR + k2) * 64);
#pragma unroll
            for (int j = 0; j < 8; ++j) {
                float u = 0.5625f * bf2f((ushort)y00[j]) + 0.1875f * bf2f((ushort)y01[j]) +
                          0.1875f * bf2f((ushort)y10[j]) + 0.0625f * bf2f((ushort)y11[j]);
                acc = fmaf(wb[j * 9 + oh * 3 + ow], u, acc);
            }
        }
    }
    acc += __shfl_xor(acc, 1, 64);
    acc += __shfl_xor(acc, 2, 64);
    acc += __shfl_xor(acc, 4, 64);
    if (icg == 0)
        xsr[(size_t)(b * 3 + o) * HHR * WHR + (size_t)n * WHR + m] = acc + b3[o];
}

extern "C" void kernel_launch(void* const* d_in, const int* in_sizes, int n_in,
                              void* d_out, int out_size, void* d_ws, size_t ws_size,
                              hipStream_t stream) {
    const float* x_hr = (const float*)d_in[0];
    const float* gains = (const float*)d_in[1];
    const float* sigp = (const float*)d_in[2];
    const float* gamp = (const float*)d_in[3];
    const float* w1 = (const float*)d_in[4];
    const float* b1 = (const float*)d_in[5];
    const float* w2 = (const float*)d_in[6];
    const float* b2 = (const float*)d_in[7];
    const float* w3 = (const float*)d_in[8];
    const float* b3 = (const float*)d_in[9];

    float* out = (float*)d_out;
    float* x_sr = out;                                  // 4*3*512*512
    float* x_lr = out + (size_t)BATCH * 3 * HHR * WHR;  // 4*3*256*256

    ushort* wsu = (ushort*)d_ws;
    ushort* Bp2 = wsu;                                  // 36864
    ushort* Bp3 = Bp2 + 36864;                          // 16384
    ushort* Bp1 = Bp3 + 16384;                          // 6144
    ushort* y1 = Bp1 + 6144;                            // 4*256*256*64 bf16
    ushort* y2 = y1 + (size_t)BATCH * HLR * WLR * 64;   // 4*256*256*64 bf16

    k_front<<<dim3(16, 16, 13), dim3(256), 0, stream>>>(
        x_hr, gains, sigp, gamp, x_lr, w1, w2, w3, Bp1, Bp2, Bp3);
    k_conv1_mfma<<<dim3(16, 64, BATCH), dim3(256), 0, stream>>>(x_lr, Bp1, b1, y1);
    k_conv2_mfma<<<dim3(16, 64, BATCH), dim3(256), 0, stream>>>(y1, Bp2, b2, y2);
    k_upc3<<<dim3(16, 32, BATCH), dim3(256), 0, stream>>>(y2, Bp3, b3, x_sr);
    k_fixframe<<<dim3((BATCH * 3 * 2044 * 8 + 255) / 256), dim3(256), 0, stream>>>(
        y2, w3, b3, x_sr);
}

// Round 14
// 89.450 us; speedup vs baseline: 1.0675x; 1.0675x over previous
//
#include <hip/hip_runtime.h>
#include <math.h>

#define BATCH 4
#define HLR 256
#define WLR 256
#define HHR 512
#define WHR 512

typedef short s8v __attribute__((ext_vector_type(8)));
typedef float f4v __attribute__((ext_vector_type(4)));

__device__ __forceinline__ ushort f2bf(float f) {
    uint u = __builtin_bit_cast(uint, f);
    uint r = (u + 0x7FFFu + ((u >> 16) & 1u)) >> 16;
    return (ushort)r;
}
__device__ __forceinline__ float bf2f(ushort u) {
    return __builtin_bit_cast(float, ((uint)u) << 16);
}

// --------- Effective upsample weight: Av(d, e_idx, t_idx), tap offset = t-1 --------
// mm = d+e-1 in [-1,2] -> jr in [-1,1] -> taps only at offsets {-1,0,+1}: 3x3 kernel.
__device__ __forceinline__ float Avf(int d, int e, int t) {
    int mm = d + e - 1;
    int par = mm & 1;
    int jr = (mm - par) >> 1;
    int j2 = jr + (par ? 1 : -1);
    float a = 0.f;
    if (t == jr + 1) a += 0.75f;
    if (t == j2 + 1) a += 0.25f;
    return a;
}

// ============ Launch 1: z<12 -> fused down+gain+bilateral+gamma ; z==12 -> weight prep
__global__ void __launch_bounds__(256) k_front(
    const float* __restrict__ x, const float* __restrict__ gains,
    const float* __restrict__ sigp, const float* __restrict__ gamp,
    float* __restrict__ xlr,
    const float* __restrict__ w1, const float* __restrict__ w2,
    const float* __restrict__ w3, ushort* __restrict__ Bp1,
    ushort* __restrict__ Bp2, ushort* __restrict__ Bp3) {
    const int z = blockIdx.z;
    const int tid = threadIdx.x;
    if (z < 12) {
        __shared__ float tile[20][20];
        const int tx = tid & 15, ty = tid >> 4;
        const int w0 = blockIdx.x * 16, h0 = blockIdx.y * 16;
        const int bc = z;
        const int c = bc % 3;
        const float* src = x + (size_t)bc * (HHR * WHR);
        const float gain = gains[c];

        const float cw0 = -0.09375f, cw1 = 0.59375f, cw2 = 0.59375f, cw3 = -0.09375f;
        for (int i = tid; i < 400; i += 256) {
            int r = i / 20, cc = i - r * 20;
            int hh = h0 + r - 2, ww = w0 + cc - 2;
            float acc = 0.f;
#pragma unroll
            for (int kh = 0; kh < 4; ++kh) {
                int sh = 2 * hh + kh - 1;
                sh = sh < 0 ? 0 : (sh > HHR - 1 ? HHR - 1 : sh);
                const float* row = src + (size_t)sh * WHR;
                float rr = 0.f;
#pragma unroll
                for (int kw = 0; kw < 4; ++kw) {
                    int sw = 2 * ww + kw - 1;
                    sw = sw < 0 ? 0 : (sw > WHR - 1 ? WHR - 1 : sw);
                    float wk = (kw == 0) ? cw0 : (kw == 1) ? cw1 : (kw == 2) ? cw2 : cw3;
                    rr = fmaf(wk, row[sw], rr);
                }
                float wk = (kh == 0) ? cw0 : (kh == 1) ? cw1 : (kh == 2) ? cw2 : cw3;
                acc = fmaf(wk, rr, acc);
            }
            tile[r][cc] = acc * gain;
        }
        __syncthreads();

        const int h = h0 + ty, w = w0 + tx;
        float sigma = sigp[0];
        float inv2s2 = 1.0f / (2.0f * sigma * sigma);
        float invg = 1.0f / gamp[0];
        const float sp0 = 0.13533528f;
        const float sp1 = 0.60653066f;

        float center = tile[ty + 2][tx + 2];
        float wsum = 0.f, psum = 0.f;
#pragma unroll
        for (int i = 0; i < 5; ++i) {
            int sh = h + i - 2;
            sh = sh < 0 ? -sh : (sh > HLR - 1 ? 2 * (HLR - 1) - sh : sh);
            int lr = sh - h0 + 2;
            float spi = (i == 0 || i == 4) ? sp0 : (i == 2 ? 1.0f : sp1);
#pragma unroll
            for (int j = 0; j < 5; ++j) {
                int sw = w + j - 2;
                sw = sw < 0 ? -sw : (sw > WLR - 1 ? 2 * (WLR - 1) - sw : sw);
                int lc = sw - w0 + 2;
                float spj = (j == 0 || j == 4) ? sp0 : (j == 2 ? 1.0f : sp1);
                float p = tile[lr][lc];
                float d = p - center;
                float cwt = __expf(-d * d * inv2s2) * spi * spj;
                wsum += cwt;
                psum = fmaf(cwt, p, psum);
            }
        }
        float v = psum / (wsum + 1e-8f);
        v = fminf(fmaxf(v, 1e-8f), 1.0f);
        xlr[(size_t)bc * (HLR * WLR) + h * WLR + w] = __powf(v, invg);
    } else {
        int bx = blockIdx.y * 16 + blockIdx.x;  // 0..255, 204 used
        if (bx >= 204) return;
        if (bx < 144) {
            int t4 = bx * 256 + tid;
            int j = t4 & 7;
            int l = (t4 >> 3) & 63;
            int g = (t4 >> 9) & 3;
            int s = t4 >> 11;
            int k = 32 * s + (l >> 4) * 8 + j;
            int t = k >> 6;
            int ic = k & 63;
            int oc = g * 16 + (l & 15);
            Bp2[t4] = f2bf(w2[(size_t)(oc * 64 + ic) * 9 + t]);
        } else if (bx < 180) {
            // Bp3: [18][64][8] bf16 — 3x3 effective taps, K = 9*64 = 576
            int t4 = (bx - 144) * 256 + tid;  // 0..9215
            int j = t4 & 7;
            int l = (t4 >> 3) & 63;
            int s = t4 >> 9;                  // 0..17
            int col = l & 15;
            float v = 0.f;
            if (col < 12) {
                int p = col / 3, o = col % 3;
                int dy = p >> 1, dx = p & 1;
                int k = s * 32 + (l >> 4) * 8 + j;  // < 576
                int tap = k >> 6, ic = k & 63;      // tap 0..8
                int ty = tap / 3, tx = tap % 3;
#pragma unroll
                for (int oh = 0; oh < 3; ++oh)
#pragma unroll
                    for (int ow = 0; ow < 3; ++ow)
                        v += w3[(size_t)(o * 64 + ic) * 9 + oh * 3 + ow] *
                             Avf(dy, oh, ty) * Avf(dx, ow, tx);
            }
            Bp3[t4] = f2bf(v);
        } else {
            int t4 = (bx - 180) * 256 + tid;
            int j = t4 & 7;
            int l = (t4 >> 3) & 63;
            int g = (t4 >> 9) & 3;
            int s = t4 >> 11;
            int k = s * 32 + (l >> 4) * 8 + j;
            int oc = g * 16 + (l & 15);
            float v = 0.f;
            if (k < 75) {
                int tap = k / 3, ic = k % 3;
                v = w1[(size_t)oc * 75 + ic * 25 + tap];
            }
            Bp1[t4] = f2bf(v);
        }
    }
}

// ============ Launch 2: conv1 3->64, 5x5, pad 2, relu — MFMA + coalesced epilogue ==
__global__ void __launch_bounds__(256) k_conv1_mfma(
    const float* __restrict__ xlr, const ushort* __restrict__ Bp,
    const float* __restrict__ b1, ushort* __restrict__ y1) {
    __shared__ float rawt[3][8][20];
    __shared__ __align__(16) ushort Alds[64 * 104];
    const int tid = threadIdx.x;
    const int w0 = blockIdx.x * 16;
    const int h0 = blockIdx.y * 4;
    const int b = blockIdx.z;

    for (int i = tid; i < 480; i += 256) {
        int ch = i / 160;
        int rem = i - ch * 160;
        int r = rem / 20, c = rem - r * 20;
        int gh = h0 + r - 2, gw = w0 + c - 2;
        float v = 0.f;
        if (gh >= 0 && gh < HLR && gw >= 0 && gw < WLR)
            v = xlr[(size_t)(b * 3 + ch) * (HLR * WLR) + gh * WLR + gw];
        rawt[ch][r][c] = v;
    }
    __syncthreads();

    {
        const int pos = tid >> 2;
        const int kq = tid & 3;
        const int f = pos >> 4;
        const int wl = pos & 15;
#pragma unroll
        for (int m = 0; m < 3; ++m) {
            uint pk[4];
#pragma unroll
            for (int e2 = 0; e2 < 4; ++e2) {
                ushort lo, hi;
#pragma unroll
                for (int h2 = 0; h2 < 2; ++h2) {
                    int i = m * 8 + e2 * 2 + h2;
                    int t0 = i / 3;
                    int ic = i - t0 * 3;
                    int tap = kq * 8 + t0;
                    float val = 0.f;
                    if (tap < 25) {
                        int kh = tap / 5, kw = tap - (tap / 5) * 5;
                        val = rawt[ic][f + kh][wl + kw];
                    }
                    if (h2 == 0) lo = f2bf(val); else hi = f2bf(val);
                }
                pk[e2] = (uint)lo | ((uint)hi << 16);
            }
            *(int4*)(Alds + pos * 104 + kq * 24 + m * 8) =
                make_int4(pk[0], pk[1], pk[2], pk[3]);
        }
    }
    __syncthreads();

    const int lane = tid & 63;
    const int wv = tid >> 6;
    const int l15 = lane & 15;
    const int lgrp = lane >> 4;

    f4v acc[4];
#pragma unroll
    for (int f = 0; f < 4; ++f) acc[f] = (f4v){0.f, 0.f, 0.f, 0.f};

#pragma unroll
    for (int s = 0; s < 3; ++s) {
        s8v bfrag = *(const s8v*)(Bp + ((size_t)(s * 4 + wv) * 64 + lane) * 8);
#pragma unroll
        for (int f = 0; f < 4; ++f) {
            const ushort* ap = Alds + (f * 16 + l15) * 104 + s * 32 + lgrp * 8;
            s8v afrag = *(const s8v*)ap;
            acc[f] = __builtin_amdgcn_mfma_f32_16x16x32_bf16(afrag, bfrag, acc[f], 0, 0, 0);
        }
    }

    __syncthreads();
    int oc = wv * 16 + l15;
    float bias = b1[oc];
#pragma unroll
    for (int f = 0; f < 4; ++f) {
#pragma unroll
        for (int r = 0; r < 4; ++r) {
            int pos = f * 16 + lgrp * 4 + r;
            Alds[pos * 64 + oc] = f2bf(fmaxf(acc[f][r] + bias, 0.f));
        }
    }
    __syncthreads();
    const size_t base = (size_t)b * HLR * WLR * 64;
#pragma unroll
    for (int i = tid; i < 512; i += 256) {
        int pos = i >> 3, c = i & 7;
        int f = pos >> 4, wcol = pos & 15;
        int4 v = *(const int4*)(Alds + pos * 64 + c * 8);
        *(int4*)(y1 + base + (size_t)((h0 + f) * WLR + (w0 + wcol)) * 64 + c * 8) = v;
    }
}

// ============ Launch 3: conv2 64->64, 3x3, pad1, relu — MFMA + coalesced epilogue ==
__global__ void __launch_bounds__(256) k_conv2_mfma(
    const ushort* __restrict__ y1, const ushort* __restrict__ Bprep,
    const float* __restrict__ b2, ushort* __restrict__ y2) {
    __shared__ ushort lds[6 * 18 * 64];  // 13824 B
    const int tid = threadIdx.x;
    const int w0 = blockIdx.x * 16;
    const int h0 = blockIdx.y * 4;
    const int b = blockIdx.z;
    const size_t base = (size_t)b * HLR * WLR * 64;

    for (int i = tid; i < 864; i += 256) {
        int c = i & 7;
        int pos = i >> 3;
        int r = pos / 18;
        int cc = pos - r * 18;
        int gh = h0 + r - 1, gw = w0 + cc - 1;
        int4 v = make_int4(0, 0, 0, 0);
        if (gh >= 0 && gh < HLR && gw >= 0 && gw < WLR)
            v = *(const int4*)(y1 + base + (size_t)(gh * WLR + gw) * 64 + c * 8);
        int byte = pos * 128 + ((c * 16) ^ ((pos & 7) << 4));
        *(int4*)((char*)lds + byte) = v;
    }
    __syncthreads();

    const int lane = tid & 63;
    const int wv = tid >> 6;
    const int l15 = lane & 15;
    const int lgrp = lane >> 4;

    f4v acc[4];
#pragma unroll
    for (int f = 0; f < 4; ++f) acc[f] = (f4v){0.f, 0.f, 0.f, 0.f};

    const ushort* bp = Bprep + ((size_t)wv * 64 + lane) * 8;
#pragma unroll
    for (int s = 0; s < 18; ++s) {
        const int t = s >> 1;
        const int dh = t / 3 - 1;
        const int dw = t % 3 - 1;
        const int icb = (s & 1) * 64 + lgrp * 16;
        s8v bfrag = *(const s8v*)(bp + (size_t)s * (4 * 64 * 8));
#pragma unroll
        for (int f = 0; f < 4; ++f) {
            int sp = (f + dh + 1) * 18 + (l15 + dw + 1);
            int byte = sp * 128 + (icb ^ ((sp & 7) << 4));
            s8v afrag = *(const s8v*)((const char*)lds + byte);
            acc[f] = __builtin_amdgcn_mfma_f32_16x16x32_bf16(afrag, bfrag, acc[f], 0, 0, 0);
        }
    }

    __syncthreads();
    int oc = wv * 16 + l15;
    float bias = b2[oc];
#pragma unroll
    for (int f = 0; f < 4; ++f) {
#pragma unroll
        for (int r = 0; r < 4; ++r) {
            int pos = f * 16 + lgrp * 4 + r;
            lds[pos * 64 + oc] = f2bf(fmaxf(acc[f][r] + bias, 0.f));
        }
    }
    __syncthreads();
#pragma unroll
    for (int i = tid; i < 512; i += 256) {
        int pos = i >> 3, c = i & 7;
        int f = pos >> 4, wcol = pos & 15;
        int4 v = *(const int4*)(lds + pos * 64 + c * 8);
        *(int4*)(y2 + base + (size_t)((h0 + f) * WLR + (w0 + wcol)) * 64 + c * 8) = v;
    }
}

// ============ Launch 4: upc3 — 3x3 effective conv, conv2-clone structure ===========
// 128 thr = 2 waves; wave = 4 LR rows x 16 cols, acc[4], 18 K-steps x 4 MFMA (= conv2).
// Halo 10x18x64 edge-clamped (23 KB). Epilogue: f32 LDS tile -> coalesced guarded
// stores (interior HR pixels; frame owned by k_fixframe).
__global__ void __launch_bounds__(128) k_upc3(
    const ushort* __restrict__ y2, const ushort* __restrict__ Bp,
    const float* __restrict__ b3, float* __restrict__ xsr) {
    __shared__ ushort lds[10 * 18 * 64];  // 23040 B (first 6 KB reused as f32 tile)
    const int tid = threadIdx.x;
    const int w0 = blockIdx.x * 16;
    const int h0 = blockIdx.y * 8;
    const int b = blockIdx.z;
    const size_t base = (size_t)b * HLR * WLR * 64;

    // stage rows h0-1..h0+8, cols w0-1..w0+16, edge-clamped, swizzled
    for (int i = tid; i < 1440; i += 128) {  // 180 pos x 8 chunks
        int c = i & 7;
        int pos = i >> 3;
        int r = pos / 18, cc = pos - r * 18;
        int gh = h0 + r - 1, gw = w0 + cc - 1;
        gh = gh < 0 ? 0 : (gh > HLR - 1 ? HLR - 1 : gh);
        gw = gw < 0 ? 0 : (gw > WLR - 1 ? WLR - 1 : gw);
        int4 v = *(const int4*)(y2 + base + (size_t)(gh * WLR + gw) * 64 + c * 8);
        int byte = pos * 128 + ((c * 16) ^ ((pos & 7) << 4));
        *(int4*)((char*)lds + byte) = v;
    }
    __syncthreads();

    const int lane = tid & 63;
    const int wv = tid >> 6;  // 0..1
    const int l15 = lane & 15;
    const int lgrp = lane >> 4;
    const int rowbase = wv * 4;

    f4v acc[4];
#pragma unroll
    for (int f = 0; f < 4; ++f) acc[f] = (f4v){0.f, 0.f, 0.f, 0.f};

    const ushort* bp = Bp + (size_t)lane * 8;
#pragma unroll
    for (int s = 0; s < 18; ++s) {
        const int tap = s >> 1;
        const int dh = tap / 3 - 1;
        const int dw = tap % 3 - 1;
        const int icb = (s & 1) * 64 + lgrp * 16;
        s8v bfrag = *(const s8v*)(bp + (size_t)s * 512);
#pragma unroll
        for (int f = 0; f < 4; ++f) {
            int sp = (rowbase + f + dh + 1) * 18 + (l15 + dw + 1);
            int byte = sp * 128 + (icb ^ ((sp & 7) << 4));
            s8v afrag = *(const s8v*)((const char*)lds + byte);
            acc[f] = __builtin_amdgcn_mfma_f32_16x16x32_bf16(afrag, bfrag, acc[f], 0, 0, 0);
        }
    }

    // epilogue: scatter to f32 LDS tile [o][nn 0..15][mm 0..31], coalesced sweeps
    __syncthreads();
    float* ldsf = (float*)lds;
    if (l15 < 12) {
        int p_ = l15 / 3;
        int o_ = l15 - p_ * 3;
        int dy = p_ >> 1, dx = p_ & 1;
        float bias = b3[o_];
#pragma unroll
        for (int f = 0; f < 4; ++f) {
            int nn = 2 * (rowbase + f) + dy;
#pragma unroll
            for (int r = 0; r < 4; ++r) {
                int mm = 2 * (lgrp * 4 + r) + dx;
                ldsf[(o_ * 16 + nn) * 32 + mm] = acc[f][r] + bias;
            }
        }
    }
    __syncthreads();
#pragma unroll
    for (int j = tid; j < 1536; j += 128) {
        int o = j >> 9;
        int rem = j & 511;
        int nn = rem >> 5, mm = rem & 31;
        int n = 2 * h0 + nn;
        int m = 2 * w0 + mm;
        if (n != 0 && n != HHR - 1 && m != 0 && m != WHR - 1)
            xsr[(size_t)(b * 3 + o) * HHR * WHR + (size_t)n * WHR + m] = ldsf[j];
    }
}

// ============ Launch 5: frame fixup — w3 staged in LDS, 8 threads per pixel ========
__global__ void __launch_bounds__(256) k_fixframe(
    const ushort* __restrict__ y2, const float* __restrict__ w3,
    const float* __restrict__ b3, float* __restrict__ xsr) {
    __shared__ float w3s[1728];  // 3*64*9 f32
    const int tid = threadIdx.x;
    for (int i = tid; i < 1728; i += 256) w3s[i] = w3[i];
    __syncthreads();

    int t = blockIdx.x * 256 + tid;
    int pix = t >> 3;
    int icg = t & 7;
    if (pix >= BATCH * 3 * 2044) return;
    int b = pix / (3 * 2044);
    int rem = pix - b * (3 * 2044);
    int o = rem / 2044;
    int p = rem - o * 2044;
    int n, m;
    if (p < 512) { n = 0; m = p; }
    else if (p < 1024) { n = 511; m = p - 512; }
    else if (p < 1534) { n = p - 1024 + 1; m = 0; }
    else { n = p - 1534 + 1; m = 511; }

    const ushort* Y = y2 + (size_t)b * HLR * WLR * 64 + icg * 8;
    const float* wb = w3s + (size_t)(o * 64 + icg * 8) * 9;
    float acc = 0.f;
#pragma unroll
    for (int oh = 0; oh < 3; ++oh) {
        int r = n - 1 + oh;
        if (r < 0 || r >= HHR) continue;
        int pr = r & 1;
        int jr = (r - pr) >> 1;
        int j2 = jr + (pr ? 1 : -1);
        j2 = j2 < 0 ? 0 : (j2 > HLR - 1 ? HLR - 1 : j2);
#pragma unroll
        for (int ow = 0; ow < 3; ++ow) {
            int c = m - 1 + ow;
            if (c < 0 || c >= WHR) continue;
            int pc = c & 1;
            int kc = (c - pc) >> 1;
            int k2 = kc + (pc ? 1 : -1);
            k2 = k2 < 0 ? 0 : (k2 > WLR - 1 ? WLR - 1 : k2);
            s8v y00 = *(const s8v*)(Y + (size_t)(jr * WLR + kc) * 64);
            s8v y01 = *(const s8v*)(Y + (size_t)(jr * WLR + k2) * 64);
            s8v y10 = *(const s8v*)(Y + (size_t)(j2 * WLR + kc) * 64);
            s8v y11 = *(const s8v*)(Y + (size_t)(j2 * WLR + k2) * 64);
#pragma unroll
            for (int j = 0; j < 8; ++j) {
                float u = 0.5625f * bf2f((ushort)y00[j]) + 0.1875f * bf2f((ushort)y01[j]) +
                          0.1875f * bf2f((ushort)y10[j]) + 0.0625f * bf2f((ushort)y11[j]);
                acc = fmaf(wb[j * 9 + oh * 3 + ow], u, acc);
            }
        }
    }
    acc += __shfl_xor(acc, 1, 64);
    acc += __shfl_xor(acc, 2, 64);
    acc += __shfl_xor(acc, 4, 64);
    if (icg == 0)
        xsr[(size_t)(b * 3 + o) * HHR * WHR + (size_t)n * WHR + m] = acc + b3[o];
}

extern "C" void kernel_launch(void* const* d_in, const int* in_sizes, int n_in,
                              void* d_out, int out_size, void* d_ws, size_t ws_size,
                              hipStream_t stream) {
    const float* x_hr = (const float*)d_in[0];
    const float* gains = (const float*)d_in[1];
    const float* sigp = (const float*)d_in[2];
    const float* gamp = (const float*)d_in[3];
    const float* w1 = (const float*)d_in[4];
    const float* b1 = (const float*)d_in[5];
    const float* w2 = (const float*)d_in[6];
    const float* b2 = (const float*)d_in[7];
    const float* w3 = (const float*)d_in[8];
    const float* b3 = (const float*)d_in[9];

    float* out = (float*)d_out;
    float* x_sr = out;                                  // 4*3*512*512
    float* x_lr = out + (size_t)BATCH * 3 * HHR * WHR;  // 4*3*256*256

    ushort* wsu = (ushort*)d_ws;
    ushort* Bp2 = wsu;                                  // 36864 bf16
    ushort* Bp3 = Bp2 + 36864;                          // 9216 bf16 (3x3 Weff)
    ushort* Bp1 = Bp3 + 9216;                           // 6144 bf16
    ushort* y1 = Bp1 + 6144;                            // 4*256*256*64 bf16
    ushort* y2 = y1 + (size_t)BATCH * HLR * WLR * 64;   // 4*256*256*64 bf16

    k_front<<<dim3(16, 16, 13), dim3(256), 0, stream>>>(
        x_hr, gains, sigp, gamp, x_lr, w1, w2, w3, Bp1, Bp2, Bp3);
    k_conv1_mfma<<<dim3(16, 64, BATCH), dim3(256), 0, stream>>>(x_lr, Bp1, b1, y1);
    k_conv2_mfma<<<dim3(16, 64, BATCH), dim3(256), 0, stream>>>(y1, Bp2, b2, y2);
    k_upc3<<<dim3(16, 32, BATCH), dim3(128), 0, stream>>>(y2, Bp3, b3, x_sr);
    k_fixframe<<<dim3((BATCH * 3 * 2044 * 8 + 255) / 256), dim3(256), 0, stream>>>(
        y2, w3, b3, x_sr);
}

// Round 15
// 82.105 us; speedup vs baseline: 1.1630x; 1.0895x over previous
//
#include <hip/hip_runtime.h>
#include <math.h>

#define BATCH 4
#define HLR 256
#define WLR 256
#define HHR 512
#define WHR 512

typedef short s8v __attribute__((ext_vector_type(8)));
typedef float f4v __attribute__((ext_vector_type(4)));

__device__ __forceinline__ ushort f2bf(float f) {
    uint u = __builtin_bit_cast(uint, f);
    uint r = (u + 0x7FFFu + ((u >> 16) & 1u)) >> 16;
    return (ushort)r;
}
__device__ __forceinline__ float bf2f(ushort u) {
    return __builtin_bit_cast(float, ((uint)u) << 16);
}

// --------- Effective upsample weight: 3x3 on LR grid (tap offsets -1..+1) ----------
__device__ __forceinline__ float Avf(int d, int e, int t) {
    int mm = d + e - 1;
    int par = mm & 1;
    int jr = (mm - par) >> 1;
    int j2 = jr + (par ? 1 : -1);
    float a = 0.f;
    if (t == jr + 1) a += 0.75f;
    if (t == j2 + 1) a += 0.25f;
    return a;
}

// ============ Launch 1: z<12 -> fused down+gain+bilateral+gamma ; z==12 -> weight prep
__global__ void __launch_bounds__(256) k_front(
    const float* __restrict__ x, const float* __restrict__ gains,
    const float* __restrict__ sigp, const float* __restrict__ gamp,
    float* __restrict__ xlr,
    const float* __restrict__ w1, const float* __restrict__ w2,
    const float* __restrict__ w3, ushort* __restrict__ Bp1,
    ushort* __restrict__ Bp2, ushort* __restrict__ Bp3) {
    const int z = blockIdx.z;
    const int tid = threadIdx.x;
    if (z < 12) {
        __shared__ float tile[20][20];
        const int tx = tid & 15, ty = tid >> 4;
        const int w0 = blockIdx.x * 16, h0 = blockIdx.y * 16;
        const int bc = z;
        const int c = bc % 3;
        const float* src = x + (size_t)bc * (HHR * WHR);
        const float gain = gains[c];

        const float cw0 = -0.09375f, cw1 = 0.59375f, cw2 = 0.59375f, cw3 = -0.09375f;
        for (int i = tid; i < 400; i += 256) {
            int r = i / 20, cc = i - r * 20;
            int hh = h0 + r - 2, ww = w0 + cc - 2;
            float acc = 0.f;
#pragma unroll
            for (int kh = 0; kh < 4; ++kh) {
                int sh = 2 * hh + kh - 1;
                sh = sh < 0 ? 0 : (sh > HHR - 1 ? HHR - 1 : sh);
                const float* row = src + (size_t)sh * WHR;
                float rr = 0.f;
#pragma unroll
                for (int kw = 0; kw < 4; ++kw) {
                    int sw = 2 * ww + kw - 1;
                    sw = sw < 0 ? 0 : (sw > WHR - 1 ? WHR - 1 : sw);
                    float wk = (kw == 0) ? cw0 : (kw == 1) ? cw1 : (kw == 2) ? cw2 : cw3;
                    rr = fmaf(wk, row[sw], rr);
                }
                float wk = (kh == 0) ? cw0 : (kh == 1) ? cw1 : (kh == 2) ? cw2 : cw3;
                acc = fmaf(wk, rr, acc);
            }
            tile[r][cc] = acc * gain;
        }
        __syncthreads();

        const int h = h0 + ty, w = w0 + tx;
        float sigma = sigp[0];
        float inv2s2 = 1.0f / (2.0f * sigma * sigma);
        float invg = 1.0f / gamp[0];
        const float sp0 = 0.13533528f;
        const float sp1 = 0.60653066f;

        float center = tile[ty + 2][tx + 2];
        float wsum = 0.f, psum = 0.f;
#pragma unroll
        for (int i = 0; i < 5; ++i) {
            int sh = h + i - 2;
            sh = sh < 0 ? -sh : (sh > HLR - 1 ? 2 * (HLR - 1) - sh : sh);
            int lr = sh - h0 + 2;
            float spi = (i == 0 || i == 4) ? sp0 : (i == 2 ? 1.0f : sp1);
#pragma unroll
            for (int j = 0; j < 5; ++j) {
                int sw = w + j - 2;
                sw = sw < 0 ? -sw : (sw > WLR - 1 ? 2 * (WLR - 1) - sw : sw);
                int lc = sw - w0 + 2;
                float spj = (j == 0 || j == 4) ? sp0 : (j == 2 ? 1.0f : sp1);
                float p = tile[lr][lc];
                float d = p - center;
                float cwt = __expf(-d * d * inv2s2) * spi * spj;
                wsum += cwt;
                psum = fmaf(cwt, p, psum);
            }
        }
        float v = psum / (wsum + 1e-8f);
        v = fminf(fmaxf(v, 1e-8f), 1.0f);
        xlr[(size_t)bc * (HLR * WLR) + h * WLR + w] = __powf(v, invg);
    } else {
        int bx = blockIdx.y * 16 + blockIdx.x;  // 0..255, 204 used
        if (bx >= 204) return;
        if (bx < 144) {
            int t4 = bx * 256 + tid;
            int j = t4 & 7;
            int l = (t4 >> 3) & 63;
            int g = (t4 >> 9) & 3;
            int s = t4 >> 11;
            int k = 32 * s + (l >> 4) * 8 + j;
            int t = k >> 6;
            int ic = k & 63;
            int oc = g * 16 + (l & 15);
            Bp2[t4] = f2bf(w2[(size_t)(oc * 64 + ic) * 9 + t]);
        } else if (bx < 180) {
            // Bp3: [18][64][8] bf16 — 3x3 effective taps, K = 9*64 = 576
            int t4 = (bx - 144) * 256 + tid;  // 0..9215
            int j = t4 & 7;
            int l = (t4 >> 3) & 63;
            int s = t4 >> 9;                  // 0..17
            int col = l & 15;
            float v = 0.f;
            if (col < 12) {
                int p = col / 3, o = col % 3;
                int dy = p >> 1, dx = p & 1;
                int k = s * 32 + (l >> 4) * 8 + j;  // < 576
                int tap = k >> 6, ic = k & 63;      // tap 0..8
                int ty = tap / 3, tx = tap % 3;
#pragma unroll
                for (int oh = 0; oh < 3; ++oh)
#pragma unroll
                    for (int ow = 0; ow < 3; ++ow)
                        v += w3[(size_t)(o * 64 + ic) * 9 + oh * 3 + ow] *
                             Avf(dy, oh, ty) * Avf(dx, ow, tx);
            }
            Bp3[t4] = f2bf(v);
        } else {
            int t4 = (bx - 180) * 256 + tid;
            int j = t4 & 7;
            int l = (t4 >> 3) & 63;
            int g = (t4 >> 9) & 3;
            int s = t4 >> 11;
            int k = s * 32 + (l >> 4) * 8 + j;
            int oc = g * 16 + (l & 15);
            float v = 0.f;
            if (k < 75) {
                int tap = k / 3, ic = k % 3;
                v = w1[(size_t)oc * 75 + ic * 25 + tap];
            }
            Bp1[t4] = f2bf(v);
        }
    }
}

// ============ Launch 2: conv1 3->64, 5x5, pad 2, relu — MFMA + coalesced epilogue ==
__global__ void __launch_bounds__(256) k_conv1_mfma(
    const float* __restrict__ xlr, const ushort* __restrict__ Bp,
    const float* __restrict__ b1, ushort* __restrict__ y1) {
    __shared__ float rawt[3][8][20];
    __shared__ __align__(16) ushort Alds[64 * 104];
    const int tid = threadIdx.x;
    const int w0 = blockIdx.x * 16;
    const int h0 = blockIdx.y * 4;
    const int b = blockIdx.z;

    for (int i = tid; i < 480; i += 256) {
        int ch = i / 160;
        int rem = i - ch * 160;
        int r = rem / 20, c = rem - r * 20;
        int gh = h0 + r - 2, gw = w0 + c - 2;
        float v = 0.f;
        if (gh >= 0 && gh < HLR && gw >= 0 && gw < WLR)
            v = xlr[(size_t)(b * 3 + ch) * (HLR * WLR) + gh * WLR + gw];
        rawt[ch][r][c] = v;
    }
    __syncthreads();

    {
        const int pos = tid >> 2;
        const int kq = tid & 3;
        const int f = pos >> 4;
        const int wl = pos & 15;
#pragma unroll
        for (int m = 0; m < 3; ++m) {
            uint pk[4];
#pragma unroll
            for (int e2 = 0; e2 < 4; ++e2) {
                ushort lo, hi;
#pragma unroll
                for (int h2 = 0; h2 < 2; ++h2) {
                    int i = m * 8 + e2 * 2 + h2;
                    int t0 = i / 3;
                    int ic = i - t0 * 3;
                    int tap = kq * 8 + t0;
                    float val = 0.f;
                    if (tap < 25) {
                        int kh = tap / 5, kw = tap - (tap / 5) * 5;
                        val = rawt[ic][f + kh][wl + kw];
                    }
                    if (h2 == 0) lo = f2bf(val); else hi = f2bf(val);
                }
                pk[e2] = (uint)lo | ((uint)hi << 16);
            }
            *(int4*)(Alds + pos * 104 + kq * 24 + m * 8) =
                make_int4(pk[0], pk[1], pk[2], pk[3]);
        }
    }
    __syncthreads();

    const int lane = tid & 63;
    const int wv = tid >> 6;
    const int l15 = lane & 15;
    const int lgrp = lane >> 4;

    f4v acc[4];
#pragma unroll
    for (int f = 0; f < 4; ++f) acc[f] = (f4v){0.f, 0.f, 0.f, 0.f};

#pragma unroll
    for (int s = 0; s < 3; ++s) {
        s8v bfrag = *(const s8v*)(Bp + ((size_t)(s * 4 + wv) * 64 + lane) * 8);
#pragma unroll
        for (int f = 0; f < 4; ++f) {
            const ushort* ap = Alds + (f * 16 + l15) * 104 + s * 32 + lgrp * 8;
            s8v afrag = *(const s8v*)ap;
            acc[f] = __builtin_amdgcn_mfma_f32_16x16x32_bf16(afrag, bfrag, acc[f], 0, 0, 0);
        }
    }

    __syncthreads();
    int oc = wv * 16 + l15;
    float bias = b1[oc];
#pragma unroll
    for (int f = 0; f < 4; ++f) {
#pragma unroll
        for (int r = 0; r < 4; ++r) {
            int pos = f * 16 + lgrp * 4 + r;
            Alds[pos * 64 + oc] = f2bf(fmaxf(acc[f][r] + bias, 0.f));
        }
    }
    __syncthreads();
    const size_t base = (size_t)b * HLR * WLR * 64;
#pragma unroll
    for (int i = tid; i < 512; i += 256) {
        int pos = i >> 3, c = i & 7;
        int f = pos >> 4, wcol = pos & 15;
        int4 v = *(const int4*)(Alds + pos * 64 + c * 8);
        *(int4*)(y1 + base + (size_t)((h0 + f) * WLR + (w0 + wcol)) * 64 + c * 8) = v;
    }
}

// ============ Launch 3: conv2 64->64, 3x3, pad1, relu — MFMA + coalesced epilogue ==
__global__ void __launch_bounds__(256) k_conv2_mfma(
    const ushort* __restrict__ y1, const ushort* __restrict__ Bprep,
    const float* __restrict__ b2, ushort* __restrict__ y2) {
    __shared__ ushort lds[6 * 18 * 64];  // 13824 B
    const int tid = threadIdx.x;
    const int w0 = blockIdx.x * 16;
    const int h0 = blockIdx.y * 4;
    const int b = blockIdx.z;
    const size_t base = (size_t)b * HLR * WLR * 64;

    for (int i = tid; i < 864; i += 256) {
        int c = i & 7;
        int pos = i >> 3;
        int r = pos / 18;
        int cc = pos - r * 18;
        int gh = h0 + r - 1, gw = w0 + cc - 1;
        int4 v = make_int4(0, 0, 0, 0);
        if (gh >= 0 && gh < HLR && gw >= 0 && gw < WLR)
            v = *(const int4*)(y1 + base + (size_t)(gh * WLR + gw) * 64 + c * 8);
        int byte = pos * 128 + ((c * 16) ^ ((pos & 7) << 4));
        *(int4*)((char*)lds + byte) = v;
    }
    __syncthreads();

    const int lane = tid & 63;
    const int wv = tid >> 6;
    const int l15 = lane & 15;
    const int lgrp = lane >> 4;

    f4v acc[4];
#pragma unroll
    for (int f = 0; f < 4; ++f) acc[f] = (f4v){0.f, 0.f, 0.f, 0.f};

    const ushort* bp = Bprep + ((size_t)wv * 64 + lane) * 8;
#pragma unroll
    for (int s = 0; s < 18; ++s) {
        const int t = s >> 1;
        const int dh = t / 3 - 1;
        const int dw = t % 3 - 1;
        const int icb = (s & 1) * 64 + lgrp * 16;
        s8v bfrag = *(const s8v*)(bp + (size_t)s * (4 * 64 * 8));
#pragma unroll
        for (int f = 0; f < 4; ++f) {
            int sp = (f + dh + 1) * 18 + (l15 + dw + 1);
            int byte = sp * 128 + (icb ^ ((sp & 7) << 4));
            s8v afrag = *(const s8v*)((const char*)lds + byte);
            acc[f] = __builtin_amdgcn_mfma_f32_16x16x32_bf16(afrag, bfrag, acc[f], 0, 0, 0);
        }
    }

    __syncthreads();
    int oc = wv * 16 + l15;
    float bias = b2[oc];
#pragma unroll
    for (int f = 0; f < 4; ++f) {
#pragma unroll
        for (int r = 0; r < 4; ++r) {
            int pos = f * 16 + lgrp * 4 + r;
            lds[pos * 64 + oc] = f2bf(fmaxf(acc[f][r] + bias, 0.f));
        }
    }
    __syncthreads();
#pragma unroll
    for (int i = tid; i < 512; i += 256) {
        int pos = i >> 3, c = i & 7;
        int f = pos >> 4, wcol = pos & 15;
        int4 v = *(const int4*)(lds + pos * 64 + c * 8);
        *(int4*)(y2 + base + (size_t)((h0 + f) * WLR + (w0 + wcol)) * 64 + c * 8) = v;
    }
}

// ============ Launch 4: z<4 -> upc3 (4x32 tile, 4 waves) ; z>=4 -> frame fixup =====
// Interior: block = 4 LR rows x 32 cols, 4 waves (wv>>1 = row pair, wv&1 = col half),
// wave = 2 rows x 16 cols, acc[2], 18 K-steps x 2 MFMA. Halo 6x34x64 = 26.1 KB ->
// 6 blocks/CU = 24 waves/CU. Epilogue: 3x8x64 f32 LDS tile -> coalesced sweeps.
__global__ void __launch_bounds__(256) k_upc3fix(
    const ushort* __restrict__ y2, const ushort* __restrict__ Bp,
    const float* __restrict__ w3, const float* __restrict__ b3,
    float* __restrict__ xsr) {
    __shared__ ushort lds[6 * 34 * 64];  // 26112 B (reused: f32 out tile / w3s)
    const int tid = threadIdx.x;
    const int z = blockIdx.z;
    const int lane = tid & 63;
    const int wv = tid >> 6;

    if (z < 4) {
        const int w0 = blockIdx.x * 32;
        const int h0 = blockIdx.y * 4;
        const int b = z;
        const size_t base = (size_t)b * HLR * WLR * 64;

        // stage rows h0-1..h0+4, cols w0-1..w0+32, edge-clamped, swizzled
        for (int i = tid; i < 1632; i += 256) {  // 204 pos x 8 chunks
            int c = i & 7;
            int pos = i >> 3;
            int r = pos / 34, cc = pos - r * 34;
            int gh = h0 + r - 1, gw = w0 + cc - 1;
            gh = gh < 0 ? 0 : (gh > HLR - 1 ? HLR - 1 : gh);
            gw = gw < 0 ? 0 : (gw > WLR - 1 ? WLR - 1 : gw);
            int4 v = *(const int4*)(y2 + base + (size_t)(gh * WLR + gw) * 64 + c * 8);
            int byte = pos * 128 + ((c * 16) ^ ((pos & 7) << 4));
            *(int4*)((char*)lds + byte) = v;
        }
        __syncthreads();

        const int l15 = lane & 15;
        const int lgrp = lane >> 4;
        const int rh = wv >> 1;        // row pair 0..1
        const int ch = wv & 1;         // col half 0..1

        f4v acc[2];
#pragma unroll
        for (int f = 0; f < 2; ++f) acc[f] = (f4v){0.f, 0.f, 0.f, 0.f};

        const ushort* bp = Bp + (size_t)lane * 8;
#pragma unroll
        for (int s = 0; s < 18; ++s) {
            const int tap = s >> 1;
            const int dh = tap / 3 - 1;
            const int dw = tap % 3 - 1;
            const int icb = (s & 1) * 64 + lgrp * 16;
            s8v bfrag = *(const s8v*)(bp + (size_t)s * 512);
#pragma unroll
            for (int f = 0; f < 2; ++f) {
                int sp = (rh * 2 + f + dh + 1) * 34 + (ch * 16 + l15 + dw + 1);
                int byte = sp * 128 + (icb ^ ((sp & 7) << 4));
                s8v afrag = *(const s8v*)((const char*)lds + byte);
                acc[f] = __builtin_amdgcn_mfma_f32_16x16x32_bf16(afrag, bfrag, acc[f], 0, 0, 0);
            }
        }

        // epilogue: f32 LDS tile [o][nn 0..7][mm 0..63] = 1536 floats
        __syncthreads();
        float* ldsf = (float*)lds;
        if (l15 < 12) {
            int p_ = l15 / 3;
            int o_ = l15 - p_ * 3;
            int dy = p_ >> 1, dx = p_ & 1;
            float bias = b3[o_];
#pragma unroll
            for (int f = 0; f < 2; ++f) {
                int nn = 2 * (rh * 2 + f) + dy;
#pragma unroll
                for (int r = 0; r < 4; ++r) {
                    int mm = 2 * (ch * 16 + lgrp * 4 + r) + dx;
                    ldsf[(o_ * 8 + nn) * 64 + mm] = acc[f][r] + bias;
                }
            }
        }
        __syncthreads();
#pragma unroll
        for (int j = tid; j < 1536; j += 256) {
            int o = j >> 9;
            int rem = j & 511;
            int nn = rem >> 6, mm = rem & 63;
            int n = 2 * h0 + nn;
            int m = 2 * w0 + mm;
            if (n != 0 && n != HHR - 1 && m != 0 && m != WHR - 1)
                xsr[(size_t)(b * 3 + o) * HHR * WHR + (size_t)n * WHR + m] = ldsf[j];
        }
    } else {
        // frame fixup: 8 threads per HR frame pixel, w3 staged in LDS
        float* w3s = (float*)lds;  // 1728 f32 = 6912 B
        for (int i = tid; i < 1728; i += 256) w3s[i] = w3[i];
        __syncthreads();

        int lb = blockIdx.y * 8 + blockIdx.x;            // 0..511
        int t = (((z - 4) * 512 + lb) << 8) + tid;
        int pix = t >> 3;
        int icg = t & 7;
        if (pix >= BATCH * 3 * 2044) return;
        int b = pix / (3 * 2044);
        int rem = pix - b * (3 * 2044);
        int o = rem / 2044;
        int p = rem - o * 2044;
        int n, m;
        if (p < 512) { n = 0; m = p; }
        else if (p < 1024) { n = 511; m = p - 512; }
        else if (p < 1534) { n = p - 1024 + 1; m = 0; }
        else { n = p - 1534 + 1; m = 511; }

        const ushort* Y = y2 + (size_t)b * HLR * WLR * 64 + icg * 8;
        const float* wb = w3s + (size_t)(o * 64 + icg * 8) * 9;
        float acc = 0.f;
#pragma unroll
        for (int oh = 0; oh < 3; ++oh) {
            int r = n - 1 + oh;
            if (r < 0 || r >= HHR) continue;
            int pr = r & 1;
            int jr = (r - pr) >> 1;
            int j2 = jr + (pr ? 1 : -1);
            j2 = j2 < 0 ? 0 : (j2 > HLR - 1 ? HLR - 1 : j2);
#pragma unroll
            for (int ow = 0; ow < 3; ++ow) {
                int c = m - 1 + ow;
                if (c < 0 || c >= WHR) continue;
                int pc = c & 1;
                int kc = (c - pc) >> 1;
                int k2 = kc + (pc ? 1 : -1);
                k2 = k2 < 0 ? 0 : (k2 > WLR - 1 ? WLR - 1 : k2);
                s8v y00 = *(const s8v*)(Y + (size_t)(jr * WLR + kc) * 64);
                s8v y01 = *(const s8v*)(Y + (size_t)(jr * WLR + k2) * 64);
                s8v y10 = *(const s8v*)(Y + (size_t)(j2 * WLR + kc) * 64);
                s8v y11 = *(const s8v*)(Y + (size_t)(j2 * WLR + k2) * 64);
#pragma unroll
                for (int j = 0; j < 8; ++j) {
                    float u = 0.5625f * bf2f((ushort)y00[j]) + 0.1875f * bf2f((ushort)y01[j]) +
                              0.1875f * bf2f((ushort)y10[j]) + 0.0625f * bf2f((ushort)y11[j]);
                    acc = fmaf(wb[j * 9 + oh * 3 + ow], u, acc);
                }
            }
        }
        acc += __shfl_xor(acc, 1, 64);
        acc += __shfl_xor(acc, 2, 64);
        acc += __shfl_xor(acc, 4, 64);
        if (icg == 0)
            xsr[(size_t)(b * 3 + o) * HHR * WHR + (size_t)n * WHR + m] = acc + b3[o];
    }
}

extern "C" void kernel_launch(void* const* d_in, const int* in_sizes, int n_in,
                              void* d_out, int out_size, void* d_ws, size_t ws_size,
                              hipStream_t stream) {
    const float* x_hr = (const float*)d_in[0];
    const float* gains = (const float*)d_in[1];
    const float* sigp = (const float*)d_in[2];
    const float* gamp = (const float*)d_in[3];
    const float* w1 = (const float*)d_in[4];
    const float* b1 = (const float*)d_in[5];
    const float* w2 = (const float*)d_in[6];
    const float* b2 = (const float*)d_in[7];
    const float* w3 = (const float*)d_in[8];
    const float* b3 = (const float*)d_in[9];

    float* out = (float*)d_out;
    float* x_sr = out;                                  // 4*3*512*512
    float* x_lr = out + (size_t)BATCH * 3 * HHR * WHR;  // 4*3*256*256

    ushort* wsu = (ushort*)d_ws;
    ushort* Bp2 = wsu;                                  // 36864 bf16
    ushort* Bp3 = Bp2 + 36864;                          // 9216 bf16 (3x3 Weff)
    ushort* Bp1 = Bp3 + 9216;                           // 6144 bf16
    ushort* y1 = Bp1 + 6144;                            // 4*256*256*64 bf16
    ushort* y2 = y1 + (size_t)BATCH * HLR * WLR * 64;   // 4*256*256*64 bf16

    k_front<<<dim3(16, 16, 13), dim3(256), 0, stream>>>(
        x_hr, gains, sigp, gamp, x_lr, w1, w2, w3, Bp1, Bp2, Bp3);
    k_conv1_mfma<<<dim3(16, 64, BATCH), dim3(256), 0, stream>>>(x_lr, Bp1, b1, y1);
    k_conv2_mfma<<<dim3(16, 64, BATCH), dim3(256), 0, stream>>>(y1, Bp2, b2, y2);
    // z 0..3: interior (8x64 grid of 4x32 tiles); z 4..5: frame fixup
    k_upc3fix<<<dim3(8, 64, 6), dim3(256), 0, stream>>>(y2, Bp3, w3, b3, x_sr);
}